// Round 1
// 2873.111 us; speedup vs baseline: 1.1150x; 1.1150x over previous
//
#include <hip/hip_runtime.h>

#define B_ 16
#define T_ 512
#define C_ 768
#define H_ 12
#define HS_ 64
#define F_ 3840
#define MROWS (B_*T_)

typedef __attribute__((ext_vector_type(8))) _Float16 half8;
typedef __attribute__((ext_vector_type(4))) float f32x4;

__device__ inline half8 cvt8(const float* __restrict__ p){
    const float4 a = ((const float4*)p)[0];
    const float4 b = ((const float4*)p)[1];
    half8 h;
    h[0]=(_Float16)a.x; h[1]=(_Float16)a.y; h[2]=(_Float16)a.z; h[3]=(_Float16)a.w;
    h[4]=(_Float16)b.x; h[5]=(_Float16)b.y; h[6]=(_Float16)b.z; h[7]=(_Float16)b.w;
    return h;
}

// ---------------- weight prep: fp32 -> fp16, transposed to Bt[n][k] ----------------
__global__ __launch_bounds__(256) void wt_kernel(const float* __restrict__ src,
                                                 _Float16* __restrict__ dst,
                                                 const int K, const int N){
    const int idx = blockIdx.x*256 + threadIdx.x;
    if (idx >= K*N) return;
    const int k = idx / N, n = idx - k*N;
    dst[(size_t)n*K + k] = (_Float16)src[idx];
}

// Wq (H,C,HS) -> Bt[(h*64+d)][c]
__global__ __launch_bounds__(256) void wqkv_kernel(const float* __restrict__ src,
                                                   _Float16* __restrict__ dst){
    const int idx = blockIdx.x*256 + threadIdx.x;
    if (idx >= H_*C_*HS_) return;
    const int d = idx & 63;
    const int c = (idx >> 6) % C_;
    const int h = idx / (C_*HS_);
    dst[(size_t)(h*HS_ + d)*C_ + c] = (_Float16)src[idx];
}

// ---------------- rmsnorm: fp32 row -> fp16 row ----------------
__global__ __launch_bounds__(256) void rms_kernel(const float* __restrict__ src,
                                                  const float* __restrict__ w,
                                                  _Float16* __restrict__ dst){
    const int row = blockIdx.x;
    const float* x = src + (size_t)row*C_;
    const int tid = threadIdx.x;
    float v0 = x[tid], v1 = x[tid+256], v2 = x[tid+512];
    float s = v0*v0 + v1*v1 + v2*v2;
    #pragma unroll
    for (int off=1; off<64; off<<=1) s += __shfl_xor(s, off, 64);
    __shared__ float red[4];
    if ((tid&63)==0) red[tid>>6] = s;
    __syncthreads();
    s = red[0]+red[1]+red[2]+red[3];
    const float r = rsqrtf(s*(1.0f/C_) + 1e-5f);
    _Float16* d = dst + (size_t)row*C_;
    d[tid]     = (_Float16)(v0*r*w[tid]);
    d[tid+256] = (_Float16)(v1*r*w[tid+256]);
    d[tid+512] = (_Float16)(v2*r*w[tid+512]);
}

// ---------------- generic MFMA GEMM: C = A(MxK) * Bt(NxK)^T + epilogue ----------------
// layout 0: row-major (m,n). 1: q/k scatter (B,H,T,HS). 2: v scatter (B,H,HS,T).
template<int KD>
__global__ __launch_bounds__(256) void gemm_kernel(
    const _Float16* __restrict__ A, const _Float16* __restrict__ Bt,
    const int Ndim,
    const float* __restrict__ bias,
    const float* __restrict__ resid,
    float* __restrict__ outf, _Float16* __restrict__ outh,
    const int layout, const int gelu)
{
    const int wave = threadIdx.x >> 6, ln = threadIdx.x & 63;
    const int lm = ln & 15, lq = ln >> 4;
    const int m0 = blockIdx.x*64 + wave*16;
    const int n0 = blockIdx.y*64;
    const _Float16* Ap  = A  + (size_t)(m0+lm)*KD + lq*8;
    const _Float16* Bp0 = Bt + (size_t)(n0+lm)*KD + lq*8;
    f32x4 acc0={},acc1={},acc2={},acc3={};
    for (int k=0; k<KD; k+=32){
        half8 a  = *(const half8*)(Ap + k);
        half8 b0 = *(const half8*)(Bp0 + k);
        half8 b1 = *(const half8*)(Bp0 + (size_t)16*KD + k);
        half8 b2 = *(const half8*)(Bp0 + (size_t)32*KD + k);
        half8 b3 = *(const half8*)(Bp0 + (size_t)48*KD + k);
        acc0 = __builtin_amdgcn_mfma_f32_16x16x32_f16(a,b0,acc0,0,0,0);
        acc1 = __builtin_amdgcn_mfma_f32_16x16x32_f16(a,b1,acc1,0,0,0);
        acc2 = __builtin_amdgcn_mfma_f32_16x16x32_f16(a,b2,acc2,0,0,0);
        acc3 = __builtin_amdgcn_mfma_f32_16x16x32_f16(a,b3,acc3,0,0,0);
    }
    f32x4 accs[4] = {acc0,acc1,acc2,acc3};
    #pragma unroll
    for (int nf=0; nf<4; nf++){
        const int n = n0 + nf*16 + lm;
        const float bv = bias ? bias[n] : 0.0f;
        #pragma unroll
        for (int i=0;i<4;i++){
            const int m = m0 + lq*4 + i;
            float v = accs[nf][i] + bv;
            if (gelu) v = 0.5f*v*(1.0f + erff(v*0.70710678118f));
            if (resid) v += resid[(size_t)m*Ndim + n];
            size_t oidx;
            if (layout == 0) oidx = (size_t)m*Ndim + n;
            else {
                const int b = m >> 9, t = m & 511, h = n >> 6, d = n & 63;
                if (layout == 1) oidx = (((size_t)(b*H_+h))*T_ + t)*HS_ + d;
                else             oidx = (((size_t)(b*H_+h))*HS_ + d)*T_ + t;
            }
            if (outf) outf[oidx] = v;
            if (outh) outh[oidx] = (_Float16)v;
        }
    }
}

// ---------------- rel-pos bias (pass 2): S[b,h,t,s] = q[b,h,t,:].rel[h,t,s,:], M-dim = b ----------
__global__ __launch_bounds__(256) void relbias_kernel(const _Float16* __restrict__ qb,
                                                      const float* __restrict__ rel,
                                                      float* __restrict__ S)
{
    const int ht = blockIdx.x;
    const int h = ht >> 9, t = ht & 511;
    const int wave = threadIdx.x>>6, ln = threadIdx.x&63;
    const int s0 = (blockIdx.y*4 + wave)*16;
    const int lm = ln&15, lq = ln>>4;
    const _Float16* qp = qb + (((size_t)lm*H_ + h)*T_ + t)*HS_ + lq*8;   // m = b = lm
    const float*    rp = rel + (((size_t)h*T_ + t)*T_ + s0+lm)*HS_ + lq*8;
    half8 a0 = *(const half8*)qp;
    half8 a1 = *(const half8*)(qp+32);
    f32x4 acc = {};
    acc = __builtin_amdgcn_mfma_f32_16x16x32_f16(a0, cvt8(rp),    acc,0,0,0);
    acc = __builtin_amdgcn_mfma_f32_16x16x32_f16(a1, cvt8(rp+32), acc,0,0,0);
    #pragma unroll
    for (int i=0;i<4;i++){
        const int bb = lq*4 + i;
        S[(((size_t)bb*H_ + h)*T_ + t)*T_ + s0+lm] = acc[i];
    }
}

// ---------------- fused flash attention: qk^T (+bias/mask) -> online softmax -> PV ----------------
// grid (B*H, T/64), 256 thr; wave w owns 16 q-rows t0 = by*64 + w*16, sweeps all s in 32-chunks.
// Swapped QK (A=K, B=Q): score C-tile layout (s = lq*4+i, t = lm).
// PV (A=P^T frag built via shfl transpose, B=V in (B,H,HS,T)): O layout (t = lq*4+i, d = lm).
__device__ inline unsigned pk2h(float a, float b){
    union { _Float16 h[2]; unsigned u; } c;
    c.h[0] = (_Float16)a; c.h[1] = (_Float16)b;
    return c.u;
}

template<int CAUSAL>
__global__ __launch_bounds__(256) void flash_kernel(
    const _Float16* __restrict__ qb,
    const _Float16* __restrict__ kb,
    const _Float16* __restrict__ vt,
    const float* __restrict__ bias,   // (B,H,T,T) fp32 or nullptr
    _Float16* __restrict__ att)       // (B,T,C)
{
    const int bh = blockIdx.x;
    const int b = bh / H_, h = bh - b*H_;
    const int wave = threadIdx.x >> 6, ln = threadIdx.x & 63;
    const int lm = ln & 15, lq = ln >> 4;
    const int t0 = blockIdx.y*64 + wave*16;

    // Q fragment (B-operand, n = t = lm, k = lq*8+j, two 32-d chunks), kept in regs
    const _Float16* qp = qb + ((size_t)bh*T_ + t0 + lm)*HS_ + lq*8;
    const half8 q0 = *(const half8*)qp;
    const half8 q1 = *(const half8*)(qp + 32);
    const _Float16* kbase = kb + ((size_t)bh*T_ + lm)*HS_ + lq*8;   // + s*HS_
    const _Float16* vbase = vt + ((size_t)bh*HS_ + lm)*T_ + lq*8;   // + dt*16*T_ + s0
    const float*    bp    = CAUSAL ? (const float*)nullptr
                                   : bias + ((size_t)bh*T_ + t0 + lm)*T_ + lq*4;

    f32x4 o0={},o1={},o2={},o3={};          // O[t=lq*4+i][d = dt*16+lm], unnormalized
    float m_run = -1e30f, l_run = 0.0f;     // keyed by row t = t0+lm
    const int send = CAUSAL ? (t0 + 16) : T_;

    for (int s0 = 0; s0 < send; s0 += 32){
        // ---- QK^T swapped: a0 covers s0..s0+15, a1 covers s0+16..s0+31 ----
        const _Float16* kp = kbase + (size_t)s0*HS_;
        f32x4 a0={}, a1={};
        a0 = __builtin_amdgcn_mfma_f32_16x16x32_f16(*(const half8*)kp,             q0, a0,0,0,0);
        a0 = __builtin_amdgcn_mfma_f32_16x16x32_f16(*(const half8*)(kp+32),        q1, a0,0,0,0);
        a1 = __builtin_amdgcn_mfma_f32_16x16x32_f16(*(const half8*)(kp+16*HS_),    q0, a1,0,0,0);
        a1 = __builtin_amdgcn_mfma_f32_16x16x32_f16(*(const half8*)(kp+16*HS_+32), q1, a1,0,0,0);

        f32x4 v0, v1;
        if (CAUSAL){
            const int t = t0 + lm;
            #pragma unroll
            for (int i=0;i<4;i++){
                const int sA = s0 + lq*4 + i;
                v0[i] = (sA      > t) ? -1e30f : 8.0f*a0[i];
                v1[i] = (sA + 16 > t) ? -1e30f : 8.0f*a1[i];
            }
        } else {
            const float4 bA = *(const float4*)(bp + s0);
            const float4 bB = *(const float4*)(bp + s0 + 16);
            v0[0]=fmaf(8.0f,a0[0],bA.x); v0[1]=fmaf(8.0f,a0[1],bA.y);
            v0[2]=fmaf(8.0f,a0[2],bA.z); v0[3]=fmaf(8.0f,a0[3],bA.w);
            v1[0]=fmaf(8.0f,a1[0],bB.x); v1[1]=fmaf(8.0f,a1[1],bB.y);
            v1[2]=fmaf(8.0f,a1[2],bB.z); v1[3]=fmaf(8.0f,a1[3],bB.w);
        }

        // ---- tile max per row t=lm (reduce across lq groups) ----
        float tm = fmaxf(fmaxf(fmaxf(v0[0],v0[1]),fmaxf(v0[2],v0[3])),
                         fmaxf(fmaxf(v1[0],v1[1]),fmaxf(v1[2],v1[3])));
        tm = fmaxf(tm, __shfl_xor(tm, 16, 64));
        tm = fmaxf(tm, __shfl_xor(tm, 32, 64));
        if (!__all(tm <= m_run)){
            const float mnew = fmaxf(m_run, tm);
            const float f = __expf(m_run - mnew);     // keyed t=lm
            m_run = mnew; l_run *= f;
            #pragma unroll
            for (int i=0;i<4;i++){                    // O keyed t=lq*4+i -> fetch factor
                const float fi = __shfl(f, lq*4 + i, 64);
                o0[i]*=fi; o1[i]*=fi; o2[i]*=fi; o3[i]*=fi;
            }
        }

        // ---- P = exp(v - m); accumulate row sum (keyed lm) ----
        f32x4 p0, p1;
        #pragma unroll
        for (int i=0;i<4;i++){ p0[i]=__expf(v0[i]-m_run); p1[i]=__expf(v1[i]-m_run); }
        l_run += (p0[0]+p0[1]) + (p0[2]+p0[3]) + ((p1[0]+p1[1]) + (p1[2]+p1[3]));

        // ---- pack fp16 pairs + shuffle-transpose into PV A-fragment ----
        // target lane (lm,lq): P[t=lm][s_local = lq*8+j]
        const unsigned h01a = pk2h(p0[0],p0[1]), h23a = pk2h(p0[2],p0[3]);
        const unsigned h01b = pk2h(p1[0],p1[1]), h23b = pk2h(p1[2],p1[3]);
        const int srcA = (lq&1)*32 + lm, srcB = srcA + 16;
        const unsigned s01a = __shfl(h01a, srcA, 64), s01b = __shfl(h01b, srcA, 64);
        const unsigned s23a = __shfl(h23a, srcA, 64), s23b = __shfl(h23b, srcA, 64);
        const unsigned u01a = __shfl(h01a, srcB, 64), u01b = __shfl(h01b, srcB, 64);
        const unsigned u23a = __shfl(h23a, srcB, 64), u23b = __shfl(h23b, srcB, 64);
        const bool hi = (lq >= 2);   // s_local >= 16 -> take tile-1 values
        uint4 aw;
        aw.x = hi ? s01b : s01a;
        aw.y = hi ? s23b : s23a;
        aw.z = hi ? u01b : u01a;
        aw.w = hi ? u23b : u23a;
        const half8 pa = __builtin_bit_cast(half8, aw);

        // ---- PV: O += P * V, 4 d-tiles ----
        const _Float16* vp = vbase + s0;
        o0 = __builtin_amdgcn_mfma_f32_16x16x32_f16(pa, *(const half8*)vp,            o0,0,0,0);
        o1 = __builtin_amdgcn_mfma_f32_16x16x32_f16(pa, *(const half8*)(vp + 16*T_),  o1,0,0,0);
        o2 = __builtin_amdgcn_mfma_f32_16x16x32_f16(pa, *(const half8*)(vp + 32*T_),  o2,0,0,0);
        o3 = __builtin_amdgcn_mfma_f32_16x16x32_f16(pa, *(const half8*)(vp + 48*T_),  o3,0,0,0);
    }

    // ---- finalize: total row sum, normalize, write (B,T,C) at head offset ----
    l_run += __shfl_xor(l_run, 16, 64);
    l_run += __shfl_xor(l_run, 32, 64);
    const float inv = 1.0f / l_run;           // keyed t=lm
    _Float16* op = att + ((size_t)b*T_ + t0)*C_ + h*HS_ + lm;
    #pragma unroll
    for (int i=0;i<4;i++){
        const float fi = __shfl(inv, lq*4 + i, 64);
        _Float16* orow = op + (size_t)(lq*4 + i)*C_;
        orow[0]  = (_Float16)(o0[i]*fi);
        orow[16] = (_Float16)(o1[i]*fi);
        orow[32] = (_Float16)(o2[i]*fi);
        orow[48] = (_Float16)(o3[i]*fi);
    }
}

extern "C" void kernel_launch(void* const* d_in, const int* in_sizes, int n_in,
                              void* d_out, int out_size, void* d_ws, size_t ws_size,
                              hipStream_t stream){
    const float* x     = (const float*)d_in[0];
    const float* normw = (const float*)d_in[1];
    const float* Wq    = (const float*)d_in[2];
    const float* bq    = (const float*)d_in[3];
    const float* Wk    = (const float*)d_in[4];
    const float* bk    = (const float*)d_in[5];
    const float* Wv    = (const float*)d_in[6];
    const float* bv    = (const float*)d_in[7];
    const float* rel   = (const float*)d_in[8];
    const float* Wp    = (const float*)d_in[9];
    const float* bp    = (const float*)d_in[10];
    const float* W1    = (const float*)d_in[11];
    const float* b1    = (const float*)d_in[12];
    const float* W2    = (const float*)d_in[13];
    const float* b2    = (const float*)d_in[14];
    float* out = (float*)d_out;

    char* ws = (char*)d_ws;
    size_t off = 0;
    auto alloc = [&](size_t bytes)->char* {
        char* p = ws + off; off += (bytes + 255) & ~(size_t)255; return p;
    };
    _Float16* btq = (_Float16*)alloc((size_t)C_*C_*2);
    _Float16* btk = (_Float16*)alloc((size_t)C_*C_*2);
    _Float16* btv = (_Float16*)alloc((size_t)C_*C_*2);
    _Float16* btp = (_Float16*)alloc((size_t)C_*C_*2);
    _Float16* bt1 = (_Float16*)alloc((size_t)C_*F_*2);
    _Float16* bt2 = (_Float16*)alloc((size_t)C_*F_*2);
    _Float16* xn  = (_Float16*)alloc((size_t)MROWS*C_*2);
    _Float16* qb  = (_Float16*)alloc((size_t)MROWS*C_*2);
    _Float16* kb  = (_Float16*)alloc((size_t)MROWS*C_*2);
    _Float16* vtb = (_Float16*)alloc((size_t)MROWS*C_*2);
    float*    S   = (float*)   alloc((size_t)B_*H_*T_*T_*4);
    _Float16* att = (_Float16*)alloc((size_t)MROWS*C_*2);
    float*    x1f = (float*)   alloc((size_t)MROWS*C_*4);
    _Float16* hbuf= (_Float16*)alloc((size_t)MROWS*F_*2);

    const dim3 blk(256);
    // weight prep
    wqkv_kernel<<<dim3((H_*C_*HS_+255)/256), blk, 0, stream>>>(Wq, btq);
    wqkv_kernel<<<dim3((H_*C_*HS_+255)/256), blk, 0, stream>>>(Wk, btk);
    wqkv_kernel<<<dim3((H_*C_*HS_+255)/256), blk, 0, stream>>>(Wv, btv);
    wt_kernel<<<dim3((C_*C_+255)/256), blk, 0, stream>>>(Wp, btp, C_, C_);
    wt_kernel<<<dim3((C_*F_+255)/256), blk, 0, stream>>>(W1, bt1, C_, F_);
    wt_kernel<<<dim3((C_*F_+255)/256), blk, 0, stream>>>(W2, bt2, F_, C_);

    const dim3 g_gemm768(MROWS/64, C_/64);        // (128,12)
    const dim3 g_flash(B_*H_, T_/64);             // (192,8)

    // ---- pass 1: causal attention (fused qk+softmax+pv, no S materialization) ----
    rms_kernel<<<dim3(MROWS), blk, 0, stream>>>(x, normw, xn);
    gemm_kernel<C_><<<g_gemm768, blk, 0, stream>>>(xn, btq, C_, bq, nullptr, nullptr, qb, 1, 0);
    gemm_kernel<C_><<<g_gemm768, blk, 0, stream>>>(xn, btk, C_, bk, nullptr, nullptr, kb, 1, 0);
    gemm_kernel<C_><<<g_gemm768, blk, 0, stream>>>(xn, btv, C_, bv, nullptr, nullptr, vtb, 2, 0);
    flash_kernel<1><<<g_flash, blk, 0, stream>>>(qb, kb, vtb, nullptr, att);
    gemm_kernel<C_><<<g_gemm768, blk, 0, stream>>>(att, btp, C_, bp, x, x1f, nullptr, 0, 0);

    // ---- pass 2: unmasked attention with rel-pos bias ----
    rms_kernel<<<dim3(MROWS), blk, 0, stream>>>(x1f, normw, xn);
    gemm_kernel<C_><<<g_gemm768, blk, 0, stream>>>(xn, btq, C_, bq, nullptr, nullptr, qb, 1, 0);
    gemm_kernel<C_><<<g_gemm768, blk, 0, stream>>>(xn, btk, C_, bk, nullptr, nullptr, kb, 1, 0);
    gemm_kernel<C_><<<g_gemm768, blk, 0, stream>>>(xn, btv, C_, bv, nullptr, nullptr, vtb, 2, 0);
    relbias_kernel<<<dim3(H_*T_, T_/64), blk, 0, stream>>>(qb, rel, S);   // S = bias (fp32)
    flash_kernel<0><<<g_flash, blk, 0, stream>>>(qb, kb, vtb, S, att);
    gemm_kernel<C_><<<g_gemm768, blk, 0, stream>>>(att, btp, C_, bp, x1f, out, nullptr, 0, 0); // out = x2

    // ---- FFN ----
    rms_kernel<<<dim3(MROWS), blk, 0, stream>>>(out, normw, xn);
    gemm_kernel<C_><<<dim3(MROWS/64, F_/64), blk, 0, stream>>>(xn, bt1, F_, b1, nullptr, nullptr, hbuf, 0, 1);
    gemm_kernel<F_><<<g_gemm768, blk, 0, stream>>>(hbuf, bt2, C_, b2, out, out, nullptr, 0, 0);
}